// Round 1
// baseline (26912.674 us; speedup 1.0000x reference)
//
#include <hip/hip_runtime.h>
#include <hip/hip_bf16.h>
#include <cstdint>
#include <cstddef>

constexpr int BATCH = 64;
constexpr int SEQ   = 512;
constexpr int DIM   = 256;
constexpr int HID   = 1024;
constexpr int COUT  = 128;
constexpr int KTOT  = DIM + HID;   // 1280
constexpr int NGATE = 4 * HID;     // 4096
constexpr float ATT_SIG_W = 3.0f;

using bf16x8 = __attribute__((ext_vector_type(8))) __bf16;
using f32x4  = __attribute__((ext_vector_type(4))) float;

__device__ __forceinline__ unsigned short f2bf(float f) {
    union { float f; unsigned u; } v; v.f = f;
    unsigned u = v.u;
    u += 0x7fffu + ((u >> 16) & 1u);
    return (unsigned short)(u >> 16);
}

// ---- weight transpose+convert: out[n][k] = bf16( k<DIM ? wi[k][n] : wh[k-DIM][n] )
__global__ void transpose_weights(const float* __restrict__ wi,
                                  const float* __restrict__ wh,
                                  unsigned short* __restrict__ out, int N) {
    __shared__ float tile[64][65];
    int ntiles = N >> 6;
    int kt = blockIdx.x / ntiles;
    int nt = blockIdx.x % ntiles;
    int k0 = kt << 6, n0 = nt << 6;
    int a = threadIdx.x & 63, g = threadIdx.x >> 6;
#pragma unroll
    for (int p = 0; p < 16; ++p) {
        int kr = p * 4 + g;
        int k = k0 + kr;
        const float* src = (k < DIM) ? (wi + (size_t)k * N) : (wh + (size_t)(k - DIM) * N);
        tile[kr][a] = src[n0 + a];
    }
    __syncthreads();
#pragma unroll
    for (int p = 0; p < 16; ++p) {
        int nr = p * 4 + g;
        out[(size_t)(n0 + nr) * KTOT + (k0 + a)] = f2bf(tile[a][nr]);
    }
}

// ---- x [B][T][D] f32 -> xt [T][B][D] bf16
__global__ void transpose_x(const float* __restrict__ x, unsigned short* __restrict__ xt) {
    size_t idx = (size_t)blockIdx.x * blockDim.x + threadIdx.x;
    if (idx >= (size_t)SEQ * BATCH * DIM) return;
    int d = idx % DIM;
    size_t r = idx / DIM;
    int b = r % BATCH;
    int t = r / BATCH;
    xt[idx] = f2bf(x[((size_t)b * SEQ + t) * DIM + d]);
}

// ---- one LSTM step, fwd+bwd fused. grid: 128 blocks x 256 thr.
// block bx: dir = bx>>6, h-col group nb = bx&63 (16 h-cols). wave w = gate w.
__global__ __launch_bounds__(256)
void lstm_step(const unsigned short* __restrict__ xt,    // [T][B][D] bf16
               const unsigned short* __restrict__ Wf,    // [4096][1280] bf16 (W_T)
               const unsigned short* __restrict__ Wb,
               const float* __restrict__ bias_f,         // [4096]
               const float* __restrict__ bias_b,
               const float* __restrict__ attw,           // att_fc_w [2048]
               unsigned short* __restrict__ h_lstm,      // [2 dir][2 buf][B][H] bf16
               float* __restrict__ c_lstm,               // [2 dir][B][H] f32
               float* __restrict__ att_part,             // [2][T][B][64] f32
               int t) {
    int bx = blockIdx.x;
    int dir = bx >> 6;
    int nb = bx & 63;
    int c0 = nb * 16;
    const unsigned short* W = dir ? Wb : Wf;
    int tx = dir ? (SEQ - 1 - t) : t;
    const unsigned short* xrow  = xt + (size_t)tx * BATCH * DIM;
    const unsigned short* hprev = h_lstm + ((size_t)dir * 2 + (t & 1)) * BATCH * HID;
    unsigned short*       hnext = h_lstm + ((size_t)dir * 2 + ((t + 1) & 1)) * BATCH * HID;
    float* cbuf = c_lstm + (size_t)dir * BATCH * HID;

    int wave = threadIdx.x >> 6;   // gate 0..3 (i,f,g,o)
    int lane = threadIdx.x & 63;
    int l15 = lane & 15;
    int lk8 = (lane >> 4) * 8;

    const unsigned short* wrow = W + (size_t)(wave * HID + c0 + l15) * KTOT;

    f32x4 acc[4] = {};
    for (int ks = 0; ks < KTOT / 32; ++ks) {
        int kk = ks * 32;
        bf16x8 bfrag = *(const bf16x8*)(wrow + kk + lk8);
        const unsigned short* abase;
        int astride;
        if (kk < DIM) { abase = xrow + kk + lk8;        astride = DIM; }
        else          { abase = hprev + (kk - DIM) + lk8; astride = HID; }
#pragma unroll
        for (int mt = 0; mt < 4; ++mt) {
            bf16x8 afrag = *(const bf16x8*)(abase + (size_t)(mt * 16 + l15) * astride);
            acc[mt] = __builtin_amdgcn_mfma_f32_16x16x32_bf16(afrag, bfrag, acc[mt], 0, 0, 0);
        }
    }

    __shared__ float glds[4][64][16];
#pragma unroll
    for (int mt = 0; mt < 4; ++mt)
#pragma unroll
        for (int r = 0; r < 4; ++r)
            glds[wave][mt * 16 + (lane >> 4) * 4 + r][l15] = acc[mt][r];
    __syncthreads();

    // elementwise: 64 rows x 16 cols; thread -> row b = tid>>2, sub s = tid&3 (4 cols each)
    int b = threadIdx.x >> 2;
    int s = threadIdx.x & 3;
    const float* bias = dir ? bias_b : bias_f;
    float attsum = 0.f;
#pragma unroll
    for (int q = 0; q < 4; ++q) {
        int cc = s * 4 + q;
        int col = c0 + cc;
        float gi = glds[0][b][cc] + bias[col];
        float gf = glds[1][b][cc] + bias[HID + col];
        float gg = glds[2][b][cc] + bias[2 * HID + col];
        float go = glds[3][b][cc] + bias[3 * HID + col];
        float si = 1.f / (1.f + __expf(-gi));
        float sf = 1.f / (1.f + __expf(-gf));
        float so = 1.f / (1.f + __expf(-go));
        float tg = tanhf(gg);
        float cn = sf * cbuf[(size_t)b * HID + col] + si * tg;
        float hn = so * tanhf(cn);
        cbuf[(size_t)b * HID + col] = cn;
        hnext[(size_t)b * HID + col] = f2bf(hn);
        attsum += hn * attw[dir * HID + col];
    }
    attsum += __shfl_xor(attsum, 1);
    attsum += __shfl_xor(attsum, 2);
    if (s == 0)
        att_part[(((size_t)dir * SEQ + tx) * BATCH + b) * 64 + nb] = attsum;
}

// ---- attention finalize: att[b][t] = sigmoid(3*(sum partials + bias))
__global__ void att_final(const float* __restrict__ att_part,
                          const float* __restrict__ att_fc_b,
                          float* __restrict__ out_att /* [B][T] */) {
    int idx = blockIdx.x * blockDim.x + threadIdx.x;
    if (idx >= SEQ * BATCH) return;
    int b = idx % BATCH, t = idx / BATCH;
    float sum = att_fc_b[0];
    const float* pf = att_part + ((size_t)t * BATCH + b) * 64;
    const float* pb = att_part + (((size_t)SEQ + t) * BATCH + b) * 64;
#pragma unroll 8
    for (int i = 0; i < 64; ++i) sum += pf[i] + pb[i];
    out_att[(size_t)b * SEQ + t] = 1.f / (1.f + __expf(-ATT_SIG_W * sum));
}

// ---- one TAGM step. grid: 16 blocks x 256 thr; block covers 64 cols (wave: 16 cols).
__global__ __launch_bounds__(256)
void tagm_step(const unsigned short* __restrict__ xt,
               const unsigned short* __restrict__ Wt,   // [1024][1280] bf16
               const float* __restrict__ i2h_b,
               const float* __restrict__ h2h_b,
               const float* __restrict__ att,           // [B][T]
               unsigned short* __restrict__ h_bf,       // [2][B][H]
               float* __restrict__ h_f32,               // [B][H]
               int t) {
    int c0 = blockIdx.x * 64;
    int wave = threadIdx.x >> 6, lane = threadIdx.x & 63;
    int l15 = lane & 15, lk8 = (lane >> 4) * 8;
    int colw = c0 + wave * 16;
    const unsigned short* xrow  = xt + (size_t)t * BATCH * DIM;
    const unsigned short* hprev = h_bf + (size_t)(t & 1) * BATCH * HID;
    unsigned short*       hnext = h_bf + (size_t)((t + 1) & 1) * BATCH * HID;
    const unsigned short* wrow = Wt + (size_t)(colw + l15) * KTOT;

    f32x4 acc[4] = {};
    for (int ks = 0; ks < KTOT / 32; ++ks) {
        int kk = ks * 32;
        bf16x8 bfrag = *(const bf16x8*)(wrow + kk + lk8);
        const unsigned short* abase;
        int astride;
        if (kk < DIM) { abase = xrow + kk + lk8;          astride = DIM; }
        else          { abase = hprev + (kk - DIM) + lk8; astride = HID; }
#pragma unroll
        for (int mt = 0; mt < 4; ++mt) {
            bf16x8 afrag = *(const bf16x8*)(abase + (size_t)(mt * 16 + l15) * astride);
            acc[mt] = __builtin_amdgcn_mfma_f32_16x16x32_bf16(afrag, bfrag, acc[mt], 0, 0, 0);
        }
    }

    int col = colw + l15;
    float bb = i2h_b[col] + h2h_b[col];
#pragma unroll
    for (int mt = 0; mt < 4; ++mt) {
#pragma unroll
        for (int r = 0; r < 4; ++r) {
            int row = mt * 16 + (lane >> 4) * 4 + r;
            float cand = acc[mt][r] + bb;
            cand = cand > 0.f ? cand : 0.f;
            float a = att[(size_t)row * SEQ + t];
            float hold = h_f32[(size_t)row * HID + col];
            float hn = a * cand + (1.f - a) * hold;
            h_f32[(size_t)row * HID + col] = hn;
            hnext[(size_t)row * HID + col] = f2bf(hn);
        }
    }
}

// ---- final fc: out[b][c] = h[b] . fc_w[:,c] + fc_b[c]  (f32)
__global__ void fc_kernel(const float* __restrict__ h, const float* __restrict__ fc_w,
                          const float* __restrict__ fc_b, float* __restrict__ out) {
    int idx = blockIdx.x * blockDim.x + threadIdx.x;
    if (idx >= BATCH * COUT) return;
    int c = idx % COUT, b = idx / COUT;
    float sum = fc_b[c];
    for (int k = 0; k < HID; ++k) sum += h[(size_t)b * HID + k] * fc_w[(size_t)k * COUT + c];
    out[idx] = sum;
}

extern "C" void kernel_launch(void* const* d_in, const int* in_sizes, int n_in,
                              void* d_out, int out_size, void* d_ws, size_t ws_size,
                              hipStream_t stream) {
    const float* x          = (const float*)d_in[0];
    const float* i2h_w      = (const float*)d_in[1];
    const float* i2h_b      = (const float*)d_in[2];
    const float* h2h_w      = (const float*)d_in[3];
    const float* h2h_b      = (const float*)d_in[4];
    const float* fc_w       = (const float*)d_in[5];
    const float* fc_b       = (const float*)d_in[6];
    const float* att_wi_fwd = (const float*)d_in[7];
    const float* att_wh_fwd = (const float*)d_in[8];
    const float* att_b_fwd  = (const float*)d_in[9];
    const float* att_wi_bwd = (const float*)d_in[10];
    const float* att_wh_bwd = (const float*)d_in[11];
    const float* att_b_bwd  = (const float*)d_in[12];
    const float* att_fc_w   = (const float*)d_in[13];
    const float* att_fc_b   = (const float*)d_in[14];
    float* out = (float*)d_out;

    char* ws = (char*)d_ws;
    unsigned short* WfT = (unsigned short*)(ws);                       // 4096*1280*2
    unsigned short* WbT = (unsigned short*)(ws + 10485760);            // 4096*1280*2
    unsigned short* WtT = (unsigned short*)(ws + 20971520);            // 1024*1280*2
    unsigned short* xtb = (unsigned short*)(ws + 23592960);            // 512*64*256*2
    float* att_part     = (float*)(ws + 40370176);                     // 2*512*64*64*4
    char* zero_base     = ws + 57147392;
    unsigned short* h_lstm    = (unsigned short*)(ws + 57147392);      // 2*2*64*1024*2
    float* c_lstm             = (float*)(ws + 57671680);               // 2*64*1024*4
    unsigned short* h_tagm_bf = (unsigned short*)(ws + 58195968);      // 2*64*1024*2
    float* h_tagm_f32         = (float*)(ws + 58458112);               // 64*1024*4
    // total ws use: 58720256 bytes (56 MiB)

    // zero recurrent state (must re-zero every call; replays mutate it)
    hipMemsetAsync(zero_base, 0, 58720256 - 57147392, stream);

    transpose_weights<<<20 * (NGATE / 64), 256, 0, stream>>>(att_wi_fwd, att_wh_fwd, WfT, NGATE);
    transpose_weights<<<20 * (NGATE / 64), 256, 0, stream>>>(att_wi_bwd, att_wh_bwd, WbT, NGATE);
    transpose_weights<<<20 * (HID / 64), 256, 0, stream>>>(i2h_w, h2h_w, WtT, HID);
    transpose_x<<<(SEQ * BATCH * DIM + 255) / 256, 256, 0, stream>>>(x, xtb);

    for (int t = 0; t < SEQ; ++t)
        lstm_step<<<128, 256, 0, stream>>>(xtb, WfT, WbT, att_b_fwd, att_b_bwd, att_fc_w,
                                           h_lstm, c_lstm, att_part, t);

    att_final<<<(SEQ * BATCH + 255) / 256, 256, 0, stream>>>(att_part, att_fc_b, out + BATCH * COUT);

    for (int t = 0; t < SEQ; ++t)
        tagm_step<<<16, 256, 0, stream>>>(xtb, WtT, i2h_b, h2h_b, out + BATCH * COUT,
                                          h_tagm_bf, h_tagm_f32, t);

    fc_kernel<<<(BATCH * COUT + 255) / 256, 256, 0, stream>>>(h_tagm_f32, fc_w, fc_b, out);
}

// Round 2
// 22637.415 us; speedup vs baseline: 1.1889x; 1.1889x over previous
//
#include <hip/hip_runtime.h>
#include <hip/hip_bf16.h>
#include <cstdint>
#include <cstddef>

constexpr int BATCH = 64;
constexpr int SEQ   = 512;
constexpr int DIM   = 256;
constexpr int HID   = 1024;
constexpr int COUT  = 128;
constexpr int KTOT  = DIM + HID;   // 1280
constexpr int NGATE = 4 * HID;     // 4096
constexpr float ATT_SIG_W = 3.0f;

using bf16x8 = __attribute__((ext_vector_type(8))) __bf16;
using f32x4  = __attribute__((ext_vector_type(4))) float;

__device__ __forceinline__ unsigned short f2bf(float f) {
    union { float f; unsigned u; } v; v.f = f;
    unsigned u = v.u;
    u += 0x7fffu + ((u >> 16) & 1u);
    return (unsigned short)(u >> 16);
}

__device__ __forceinline__ float sigm(float x) { return 1.f / (1.f + __expf(-x)); }

// ---- weight transpose+convert: out[n][k] = bf16( k<DIM ? wi[k][n] : wh[k-DIM][n] )
__global__ void transpose_weights(const float* __restrict__ wi,
                                  const float* __restrict__ wh,
                                  unsigned short* __restrict__ out, int N) {
    __shared__ float tile[64][65];
    int ntiles = N >> 6;
    int kt = blockIdx.x / ntiles;
    int nt = blockIdx.x % ntiles;
    int k0 = kt << 6, n0 = nt << 6;
    int a = threadIdx.x & 63, g = threadIdx.x >> 6;
#pragma unroll
    for (int p = 0; p < 16; ++p) {
        int kr = p * 4 + g;
        int k = k0 + kr;
        const float* src = (k < DIM) ? (wi + (size_t)k * N) : (wh + (size_t)(k - DIM) * N);
        tile[kr][a] = src[n0 + a];
    }
    __syncthreads();
#pragma unroll
    for (int p = 0; p < 16; ++p) {
        int nr = p * 4 + g;
        out[(size_t)(n0 + nr) * KTOT + (k0 + a)] = f2bf(tile[a][nr]);
    }
}

// ---- x [B][T][D] f32 -> xt [T][B][D] bf16
__global__ void transpose_x(const float* __restrict__ x, unsigned short* __restrict__ xt) {
    size_t idx = (size_t)blockIdx.x * blockDim.x + threadIdx.x;
    if (idx >= (size_t)SEQ * BATCH * DIM) return;
    int d = idx % DIM;
    size_t r = idx / DIM;
    int b = r % BATCH;
    int t = r / BATCH;
    xt[idx] = f2bf(x[((size_t)b * SEQ + t) * DIM + d]);
}

// ---- pack LSTM weights into per-(colgroup, khalf) MFMA fragment order.
// Region (cg,kh): 40 frags (nt*20+ksl) x 1024B; frag elem (lane,e):
//   col p = nt*16+(lane&15) -> origcol = (p>>3)*1024 + cg*8 + (p&7)
//   k = kh*640 + ksl*32 + (lane>>4)*8 + e
__global__ void pack_lstm(const unsigned short* __restrict__ WT,
                          unsigned short* __restrict__ out) {
    int cg = blockIdx.x >> 1, kh = blockIdx.x & 1;
    size_t base = (size_t)blockIdx.x * 20480;
#pragma unroll
    for (int j = 0; j < 80; ++j) {
        int idx = threadIdx.x * 80 + j;
        int frag = idx >> 9;
        int rem = idx & 511;
        int lane = rem >> 3, e = rem & 7;
        int nt = frag / 20, ksl = frag % 20;
        int p = nt * 16 + (lane & 15);
        int origcol = (p >> 3) * 1024 + cg * 8 + (p & 7);
        int k = kh * 640 + ksl * 32 + ((lane >> 4) & 3) * 8 + e;
        out[base + idx] = WT[(size_t)origcol * KTOT + k];
    }
}

// ---- pack TAGM weights: region (cg,kh): 20 frags (ksl) x 1024B; col = cg*16+(lane&15)
__global__ void pack_tagm(const unsigned short* __restrict__ WT,
                          unsigned short* __restrict__ out) {
    int cg = blockIdx.x >> 1, kh = blockIdx.x & 1;
    size_t base = (size_t)blockIdx.x * 10240;
#pragma unroll
    for (int j = 0; j < 40; ++j) {
        int idx = threadIdx.x * 40 + j;
        int ksl = idx >> 9;
        int rem = idx & 511;
        int lane = rem >> 3, e = rem & 7;
        int origcol = cg * 16 + (lane & 15);
        int k = kh * 640 + ksl * 32 + ((lane >> 4) & 3) * 8 + e;
        out[base + idx] = WT[(size_t)origcol * KTOT + k];
    }
}

// ---- device-scope step barrier: one monotone counter per barrier instance (no ABA)
__device__ __forceinline__ void barrier_sync(unsigned* slot, unsigned target) {
    __syncthreads();                 // drains each wave's vmem before s_barrier
    if (threadIdx.x == 0) {
        __threadfence();             // agent release: wbl2
        __hip_atomic_fetch_add(slot, 1u, __ATOMIC_RELAXED, __HIP_MEMORY_SCOPE_AGENT);
        while (__hip_atomic_load(slot, __ATOMIC_RELAXED, __HIP_MEMORY_SCOPE_AGENT) < target)
            __builtin_amdgcn_s_sleep(2);
        __threadfence();             // agent acquire: inv (CU-wide L1)
    }
    __syncthreads();
}

// ======== the persistent fused kernel ========
// grid 256 x 256thr; LDS 140KiB -> exactly 1 block/CU -> all blocks co-resident.
// LSTM: block = (dir = bid&1, cg = bid>>1 : 8 h-cols). wave = (mh = w>>1, kh = w&1).
// Each wave: W slice [32 packed gatecols x 640 K] in 160 VGPRs, M=32 rows.
// TAGM (bid<64): block = 16 h-cols, same wave split, W in 80 VGPRs.
__global__ __launch_bounds__(256)
void tagm_fused(const unsigned short* __restrict__ xt,
                const unsigned short* __restrict__ Wfp,
                const unsigned short* __restrict__ Wbp,
                const unsigned short* __restrict__ Wtp,
                const float* __restrict__ bias_f, const float* __restrict__ bias_b,
                const float* __restrict__ attw, const float* __restrict__ att_fc_b,
                const float* __restrict__ i2h_b, const float* __restrict__ h2h_b,
                const float* __restrict__ fc_w, const float* __restrict__ fc_b,
                unsigned short* __restrict__ h_lstm,  // [2][2][64][1024] bf16
                unsigned short* __restrict__ h_tagm,  // [2][64][1024] bf16
                float* __restrict__ h_f32,            // [64][1024]
                float* __restrict__ att_acc,          // [512][64]
                unsigned* __restrict__ bars,
                float* __restrict__ out) {
    extern __shared__ char smem[];                  // [0,131072): h stage (swizzled)
    char* dumpbase = smem + 131072;                 // 8 KB acc dump
    float* auxf = (float*)(smem + 131072 + 8192);   // 4 KB: LSTM c / TAGM h master

    int tid = threadIdx.x;
    int wave = tid >> 6, lane = tid & 63;
    int bid = blockIdx.x;
    int dir = bid & 1, cg = bid >> 1;
    int mh = wave >> 1, kh = wave & 1;
    int q = lane >> 4, c15 = lane & 15;

    // ---- LSTM weight fragments -> registers (coalesced 16B loads)
    bf16x8 wreg[40];
    {
        const unsigned short* wp = (dir ? Wbp : Wfp) + (size_t)(cg * 2 + kh) * 20480;
#pragma unroll
        for (int f = 0; f < 40; ++f)
            wreg[f] = *(const bf16x8*)(wp + f * 512 + lane * 8);
    }
    int hc = lane & 7;
    int colE = cg * 8 + hc;
    const float* bias = dir ? bias_b : bias_f;
    float b_ii = bias[colE], b_ff = bias[HID + colE];
    float b_gg = bias[2 * HID + colE], b_oo = bias[3 * HID + colE];
    float attw_l = attw[dir * HID + colE];

    for (int i = tid; i < 512; i += 256) auxf[i] = 0.f;   // c = 0
    __syncthreads();

    // =============== LSTM loop ===============
    for (int t = 0; t < SEQ; ++t) {
        int tx = dir ? (SEQ - 1 - t) : t;
        {   // stage h_prev -> LDS, XOR-swizzled rows
            const uint4* src = (const uint4*)(h_lstm + (size_t)(dir * 2 + (t & 1)) * 65536);
#pragma unroll 4
            for (int i = 0; i < 32; ++i) {
                int cidx = i * 256 + tid;
                int row = cidx >> 7, kc = cidx & 127;
                uint4 v = src[cidx];
                *(uint4*)(smem + ((unsigned)(cidx * 16) ^ ((row & 7) << 4))) = v;
            }
        }
        __syncthreads();

        f32x4 acc[2][2] = {};
        const unsigned short* xrow = xt + (size_t)tx * BATCH * DIM;
#pragma unroll
        for (int ksl = 0; ksl < 20; ++ksl) {
            int kk = kh * 640 + ksl * 32 + q * 8;
#pragma unroll
            for (int mt = 0; mt < 2; ++mt) {
                int row = mh * 32 + mt * 16 + c15;
                bf16x8 a;
                if (kh == 0 && ksl < 8) {
                    a = *(const bf16x8*)(xrow + row * DIM + kk);
                } else {
                    unsigned off = (unsigned)(row * 2048 + (kk - 256) * 2) ^ ((row & 7) << 4);
                    a = *(const bf16x8*)(smem + off);
                }
                acc[mt][0] = __builtin_amdgcn_mfma_f32_16x16x32_bf16(a, wreg[ksl],      acc[mt][0], 0, 0, 0);
                acc[mt][1] = __builtin_amdgcn_mfma_f32_16x16x32_bf16(a, wreg[20 + ksl], acc[mt][1], 0, 0, 0);
            }
        }
        if (kh == 1) {   // k-half-1 waves dump partials
            float* dp = (float*)(dumpbase + mh * 4096);
#pragma unroll
            for (int mt = 0; mt < 2; ++mt)
#pragma unroll
                for (int nt = 0; nt < 2; ++nt)
                    *(f32x4*)(dp + ((mt * 2 + nt) * 64 + lane) * 4) = acc[mt][nt];
        }
        __syncthreads();
        if (kh == 0) {   // reduce + gates + state update (waves 0,2 in parallel)
            const float* dp = (const float*)(dumpbase + mh * 4096);
            unsigned short* hnext = h_lstm + (size_t)(dir * 2 + ((t + 1) & 1)) * 65536;
            bool low = (lane & 8) == 0;
#pragma unroll
            for (int mt = 0; mt < 2; ++mt) {
                f32x4 g0 = acc[mt][0] + *(const f32x4*)(dp + ((mt * 2 + 0) * 64 + lane) * 4);
                f32x4 g1 = acc[mt][1] + *(const f32x4*)(dp + ((mt * 2 + 1) * 64 + lane) * 4);
#pragma unroll
                for (int r = 0; r < 4; ++r) {
                    float fo0 = __shfl(g0[r], lane ^ 8);   // f gate from partner lane
                    float fo1 = __shfl(g1[r], lane ^ 8);   // o gate from partner lane
                    int row = mh * 32 + mt * 16 + q * 4 + r;
                    float si = sigm(g0[r] + b_ii);
                    float sf = sigm(fo0 + b_ff);
                    float tg = tanhf(g1[r] + b_gg);
                    float so = sigm(fo1 + b_oo);
                    float cprev = auxf[row * 8 + hc];
                    float cn = sf * cprev + si * tg;
                    float hn = so * tanhf(cn);
                    float av = low ? hn * attw_l : 0.f;
                    av += __shfl_xor(av, 1); av += __shfl_xor(av, 2); av += __shfl_xor(av, 4);
                    if (low) {
                        auxf[row * 8 + hc] = cn;
                        hnext[row * HID + colE] = f2bf(hn);
                    }
                    if ((lane & 15) == 0)
                        atomicAdd(att_acc + tx * 64 + row, av);
                }
            }
        }
        barrier_sync(bars + dir * 512 + t, 128);
    }

    // =============== attention finalize ===============
    barrier_sync(bars + 1024, 256);
    {
        float ab = att_fc_b[0];
        for (int i = tid; i < 128; i += 256) {
            int item = bid * 128 + i;            // = t*64 + row
            int tt = item >> 6, row = item & 63;
            out[BATCH * COUT + row * SEQ + tt] = sigm(ATT_SIG_W * (att_acc[item] + ab));
        }
    }
    barrier_sync(bars + 1025, 256);
    if (bid >= 64) return;

    // =============== TAGM loop (64 blocks) ===============
    bf16x8 wt[20];
    {
        const unsigned short* wp = Wtp + (size_t)(bid * 2 + kh) * 10240;
#pragma unroll
        for (int f = 0; f < 20; ++f)
            wt[f] = *(const bf16x8*)(wp + f * 512 + lane * 8);
    }
    int colT = bid * 16 + c15;
    float bbT = i2h_b[colT] + h2h_b[colT];
    for (int i = tid; i < 1024; i += 256) auxf[i] = 0.f;   // h master = 0
    __syncthreads();
    const float* attd = out + BATCH * COUT;

    for (int t = 0; t < SEQ; ++t) {
        {
            const uint4* src = (const uint4*)(h_tagm + (size_t)(t & 1) * 65536);
#pragma unroll 4
            for (int i = 0; i < 32; ++i) {
                int cidx = i * 256 + tid;
                int row = cidx >> 7;
                uint4 v = src[cidx];
                *(uint4*)(smem + ((unsigned)(cidx * 16) ^ ((row & 7) << 4))) = v;
            }
        }
        __syncthreads();
        f32x4 acc[2] = {};
        const unsigned short* xrow = xt + (size_t)t * BATCH * DIM;
#pragma unroll
        for (int ksl = 0; ksl < 20; ++ksl) {
            int kk = kh * 640 + ksl * 32 + q * 8;
#pragma unroll
            for (int mt = 0; mt < 2; ++mt) {
                int row = mh * 32 + mt * 16 + c15;
                bf16x8 a;
                if (kh == 0 && ksl < 8) {
                    a = *(const bf16x8*)(xrow + row * DIM + kk);
                } else {
                    unsigned off = (unsigned)(row * 2048 + (kk - 256) * 2) ^ ((row & 7) << 4);
                    a = *(const bf16x8*)(smem + off);
                }
                acc[mt] = __builtin_amdgcn_mfma_f32_16x16x32_bf16(a, wt[ksl], acc[mt], 0, 0, 0);
            }
        }
        if (kh == 1) {
            float* dp = (float*)(dumpbase + mh * 2048);
            *(f32x4*)(dp + (0 * 64 + lane) * 4) = acc[0];
            *(f32x4*)(dp + (1 * 64 + lane) * 4) = acc[1];
        }
        __syncthreads();
        if (kh == 0) {
            const float* dp = (const float*)(dumpbase + mh * 2048);
            unsigned short* hnext = h_tagm + (size_t)((t + 1) & 1) * 65536;
#pragma unroll
            for (int mt = 0; mt < 2; ++mt) {
                f32x4 g = acc[mt] + *(const f32x4*)(dp + (mt * 64 + lane) * 4);
#pragma unroll
                for (int r = 0; r < 4; ++r) {
                    int row = mh * 32 + mt * 16 + q * 4 + r;
                    float cand = g[r] + bbT;
                    cand = cand > 0.f ? cand : 0.f;
                    float a = attd[row * SEQ + t];
                    float hold = auxf[row * 16 + c15];
                    float hn = a * cand + (1.f - a) * hold;
                    auxf[row * 16 + c15] = hn;
                    hnext[row * HID + colT] = f2bf(hn);
                }
            }
        }
        barrier_sync(bars + 1026 + t, 64);
    }

    // dump final h (f32) for FC
    for (int i = tid; i < 1024; i += 256) {
        int row = i >> 4, cl = i & 15;
        h_f32[row * HID + bid * 16 + cl] = auxf[i];
    }
    barrier_sync(bars + 1538, 64);

    // =============== FC: out[b][c], block = batch row ===============
    {
        float* fcp = (float*)dumpbase;   // [2][128]
        int c = tid & 127, half = tid >> 7;
        const float* hrow = h_f32 + (size_t)bid * HID;
        float s = 0.f;
        for (int k = half * 512; k < half * 512 + 512; ++k)
            s += hrow[k] * fc_w[(size_t)k * COUT + c];
        fcp[half * 128 + c] = s;
        __syncthreads();
        if (tid < 128)
            out[bid * COUT + tid] = fcp[tid] + fcp[128 + tid] + fc_b[tid];
    }
}

extern "C" void kernel_launch(void* const* d_in, const int* in_sizes, int n_in,
                              void* d_out, int out_size, void* d_ws, size_t ws_size,
                              hipStream_t stream) {
    const float* x          = (const float*)d_in[0];
    const float* i2h_w      = (const float*)d_in[1];
    const float* i2h_b      = (const float*)d_in[2];
    const float* h2h_w      = (const float*)d_in[3];
    const float* h2h_b      = (const float*)d_in[4];
    const float* fc_w       = (const float*)d_in[5];
    const float* fc_b       = (const float*)d_in[6];
    const float* att_wi_fwd = (const float*)d_in[7];
    const float* att_wh_fwd = (const float*)d_in[8];
    const float* att_b_fwd  = (const float*)d_in[9];
    const float* att_wi_bwd = (const float*)d_in[10];
    const float* att_wh_bwd = (const float*)d_in[11];
    const float* att_b_bwd  = (const float*)d_in[12];
    const float* att_fc_w   = (const float*)d_in[13];
    const float* att_fc_b   = (const float*)d_in[14];
    float* out = (float*)d_out;

    char* ws = (char*)d_ws;
    // phase-1 region (transposed weights; later reused for runtime state)
    unsigned short* WfT = (unsigned short*)(ws + 0);          // 4096*1280*2 = 10485760
    unsigned short* WbT = (unsigned short*)(ws + 10485760);   // 10485760
    unsigned short* WtT = (unsigned short*)(ws + 20971520);   // 1024*1280*2 = 2621440
    // packed fragment weights (persist)
    unsigned short* Wfp = (unsigned short*)(ws + 23592960);   // 10485760
    unsigned short* Wbp = (unsigned short*)(ws + 34078720);   // 10485760
    unsigned short* Wtp = (unsigned short*)(ws + 44564480);   // 2621440 -> end 47185920
    // runtime region (aliases WT region, safe: written after packs consumed WT)
    unsigned short* xtb    = (unsigned short*)(ws + 0);        // 512*64*256*2 = 16777216
    unsigned short* h_lstm = (unsigned short*)(ws + 16777216); // 524288
    unsigned short* h_tagm = (unsigned short*)(ws + 17301504); // 262144
    float*          h_f32  = (float*)(ws + 17563648);          // 262144
    float*          attacc = (float*)(ws + 17825792);          // 131072
    unsigned*       bars   = (unsigned*)(ws + 17956864);       // 8192 -> end 17965056

    transpose_weights<<<20 * (NGATE / 64), 256, 0, stream>>>(att_wi_fwd, att_wh_fwd, WfT, NGATE);
    transpose_weights<<<20 * (NGATE / 64), 256, 0, stream>>>(att_wi_bwd, att_wh_bwd, WbT, NGATE);
    transpose_weights<<<20 * (HID / 64), 256, 0, stream>>>(i2h_w, h2h_w, WtT, HID);
    pack_lstm<<<256, 256, 0, stream>>>(WfT, Wfp);
    pack_lstm<<<256, 256, 0, stream>>>(WbT, Wbp);
    pack_tagm<<<128, 256, 0, stream>>>(WtT, Wtp);
    // xt overwrites WfT region — stream-ordered after packs finished reading it
    transpose_x<<<(SEQ * BATCH * DIM + 255) / 256, 256, 0, stream>>>(x, xtb);
    // zero all runtime state (h bufs, att accumulator, barrier counters) every call
    hipMemsetAsync(ws + 16777216, 0, 17965056 - 16777216, stream);

    static const int SMEM_BYTES = 131072 + 8192 + 4096;   // 143360
    hipFuncSetAttribute(reinterpret_cast<const void*>(tagm_fused),
                        hipFuncAttributeMaxDynamicSharedMemorySize, SMEM_BYTES);
    tagm_fused<<<256, 256, SMEM_BYTES, stream>>>(
        xtb, Wfp, Wbp, Wtp, att_b_fwd, att_b_bwd, att_fc_w, att_fc_b,
        i2h_b, h2h_b, fc_w, fc_b, h_lstm, h_tagm, h_f32, attacc, bars, out);
}

// Round 3
// 19523.477 us; speedup vs baseline: 1.3785x; 1.1595x over previous
//
#include <hip/hip_runtime.h>
#include <hip/hip_bf16.h>
#include <cstdint>
#include <cstddef>

constexpr int BATCH = 64;
constexpr int SEQ   = 512;
constexpr int DIM   = 256;
constexpr int HID   = 1024;
constexpr int COUT  = 128;
constexpr int KTOT  = DIM + HID;   // 1280
constexpr int NGATE = 4 * HID;     // 4096
constexpr float ATT_SIG_W = 3.0f;

using bf16x8 = __attribute__((ext_vector_type(8))) __bf16;
using f32x4  = __attribute__((ext_vector_type(4))) float;

__device__ __forceinline__ unsigned short f2bf(float f) {
    union { float f; unsigned u; } v; v.f = f;
    unsigned u = v.u;
    u += 0x7fffu + ((u >> 16) & 1u);
    return (unsigned short)(u >> 16);
}

__device__ __forceinline__ float sigm(float x) { return 1.f / (1.f + __expf(-x)); }

// ---- weight transpose+convert: out[n][k] = bf16( k<DIM ? wi[k][n] : wh[k-DIM][n] )
__global__ void transpose_weights(const float* __restrict__ wi,
                                  const float* __restrict__ wh,
                                  unsigned short* __restrict__ out, int N) {
    __shared__ float tile[64][65];
    int ntiles = N >> 6;
    int kt = blockIdx.x / ntiles;
    int nt = blockIdx.x % ntiles;
    int k0 = kt << 6, n0 = nt << 6;
    int a = threadIdx.x & 63, g = threadIdx.x >> 6;
#pragma unroll
    for (int p = 0; p < 16; ++p) {
        int kr = p * 4 + g;
        int k = k0 + kr;
        const float* src = (k < DIM) ? (wi + (size_t)k * N) : (wh + (size_t)(k - DIM) * N);
        tile[kr][a] = src[n0 + a];
    }
    __syncthreads();
#pragma unroll
    for (int p = 0; p < 16; ++p) {
        int nr = p * 4 + g;
        out[(size_t)(n0 + nr) * KTOT + (k0 + a)] = f2bf(tile[a][nr]);
    }
}

// ---- x [B][T][D] f32 -> xt [T][B][D] bf16
__global__ void transpose_x(const float* __restrict__ x, unsigned short* __restrict__ xt) {
    size_t idx = (size_t)blockIdx.x * blockDim.x + threadIdx.x;
    if (idx >= (size_t)SEQ * BATCH * DIM) return;
    int d = idx % DIM;
    size_t r = idx / DIM;
    int b = r % BATCH;
    int t = r / BATCH;
    xt[idx] = f2bf(x[((size_t)b * SEQ + t) * DIM + d]);
}

// ---- pack LSTM weights into per-(colgroup, khalf) MFMA fragment order.
__global__ void pack_lstm(const unsigned short* __restrict__ WT,
                          unsigned short* __restrict__ out) {
    int cg = blockIdx.x >> 1, kh = blockIdx.x & 1;
    size_t base = (size_t)blockIdx.x * 20480;
#pragma unroll
    for (int j = 0; j < 80; ++j) {
        int idx = threadIdx.x * 80 + j;
        int frag = idx >> 9;
        int rem = idx & 511;
        int lane = rem >> 3, e = rem & 7;
        int nt = frag / 20, ksl = frag % 20;
        int p = nt * 16 + (lane & 15);
        int origcol = (p >> 3) * 1024 + cg * 8 + (p & 7);
        int k = kh * 640 + ksl * 32 + ((lane >> 4) & 3) * 8 + e;
        out[base + idx] = WT[(size_t)origcol * KTOT + k];
    }
}

// ---- pack TAGM weights: region (cg,kh): 20 frags x 1024B; col = cg*16+(lane&15)
__global__ void pack_tagm(const unsigned short* __restrict__ WT,
                          unsigned short* __restrict__ out) {
    int cg = blockIdx.x >> 1, kh = blockIdx.x & 1;
    size_t base = (size_t)blockIdx.x * 10240;
#pragma unroll
    for (int j = 0; j < 40; ++j) {
        int idx = threadIdx.x * 40 + j;
        int ksl = idx >> 9;
        int rem = idx & 511;
        int lane = rem >> 3, e = rem & 7;
        int origcol = cg * 16 + (lane & 15);
        int k = kh * 640 + ksl * 32 + ((lane >> 4) & 3) * 8 + e;
        out[base + idx] = WT[(size_t)origcol * KTOT + k];
    }
}

// ---- flag-array barrier: arrival = release store of epoch into own slot (no RMW),
// wave 0 polls all participant flags with relaxed loads; single acquire fence on pass.
__device__ __forceinline__ void flag_barrier(unsigned* flags, int base, int cnt,
                                             int myidx, unsigned epoch) {
    __syncthreads();   // all waves drain their vmem (waitcnt before s_barrier)
    if (threadIdx.x == 0) {
        __builtin_amdgcn_fence(__ATOMIC_RELEASE, "agent");   // wbl2: flush this XCD's dirty lines
        __hip_atomic_store(flags + myidx, epoch, __ATOMIC_RELAXED, __HIP_MEMORY_SCOPE_AGENT);
    }
    if (threadIdx.x < 64) {
        for (;;) {
            bool ok = true;
            for (int j = (int)threadIdx.x; j < cnt; j += 64)
                ok &= (__hip_atomic_load(flags + base + j, __ATOMIC_RELAXED,
                                         __HIP_MEMORY_SCOPE_AGENT) >= epoch);
            if (__all(ok)) break;
            __builtin_amdgcn_s_sleep(1);
        }
        if (threadIdx.x == 0)
            __builtin_amdgcn_fence(__ATOMIC_ACQUIRE, "agent");   // inv: L1 + stale L2
    }
    __syncthreads();
}

// ======== the persistent fused kernel ========
// grid 256 x 256thr; LDS 140KiB -> 1 block/CU -> all blocks co-resident.
// LSTM: block = (dir = bid&1, cg = bid>>1 : 8 h-cols x 4 gates). wave = (mh, kh).
// TAGM (bid<64): block = 16 h-cols.
__global__ __launch_bounds__(256)
void tagm_fused(const unsigned short* __restrict__ xt,
                const unsigned short* __restrict__ Wfp,
                const unsigned short* __restrict__ Wbp,
                const unsigned short* __restrict__ Wtp,
                const float* __restrict__ bias_f, const float* __restrict__ bias_b,
                const float* __restrict__ attw, const float* __restrict__ att_fc_b,
                const float* __restrict__ i2h_b, const float* __restrict__ h2h_b,
                const float* __restrict__ fc_w, const float* __restrict__ fc_b,
                unsigned short* __restrict__ h_lstm,  // [2][2][64][1024] bf16
                unsigned short* __restrict__ h_tagm,  // [2][64][1024] bf16
                float* __restrict__ h_f32,            // [64][1024]
                float* __restrict__ att_part,         // [256 blk][512*64] f32 (aliases Wfp/Wbp!)
                unsigned* __restrict__ flags,         // [640]
                float* __restrict__ out) {
    extern __shared__ char smem[];                  // [0,131072): h stage (swizzled)
    char* dumpbase = smem + 131072;                 // 8 KB acc dump
    float* auxf = (float*)(smem + 131072 + 8192);   // 4 KB: LSTM c / TAGM h master

    int tid = threadIdx.x;
    int wave = tid >> 6, lane = tid & 63;
    int bid = blockIdx.x;
    int dir = bid & 1, cg = bid >> 1;
    int mh = wave >> 1, kh = wave & 1;
    int q = lane >> 4, c15 = lane & 15;

    // ---- LSTM weight fragments -> registers
    bf16x8 wreg[40];
    {
        const unsigned short* wp = (dir ? Wbp : Wfp) + (size_t)(cg * 2 + kh) * 20480;
#pragma unroll
        for (int f = 0; f < 40; ++f)
            wreg[f] = *(const bf16x8*)(wp + f * 512 + lane * 8);
    }
    int hc = lane & 7;
    int colE = cg * 8 + hc;
    const float* bias = dir ? bias_b : bias_f;
    float b_ii = bias[colE], b_ff = bias[HID + colE];
    float b_gg = bias[2 * HID + colE], b_oo = bias[3 * HID + colE];
    float attw_l = attw[dir * HID + colE];

    for (int i = tid; i < 512; i += 256) auxf[i] = 0.f;   // c = 0

    // all blocks hold weights in regs before att_part may clobber Wfp/Wbp
    flag_barrier(flags, 256, 256, 256 + bid, 1u);

    // =============== LSTM loop ===============
    for (int t = 0; t < SEQ; ++t) {
        int tx = dir ? (SEQ - 1 - t) : t;
        {   // stage h_prev -> LDS, XOR-swizzled rows
            const uint4* src = (const uint4*)(h_lstm + (size_t)(dir * 2 + (t & 1)) * 65536);
#pragma unroll 4
            for (int i = 0; i < 32; ++i) {
                int cidx = i * 256 + tid;
                int row = cidx >> 7;
                uint4 v = src[cidx];
                *(uint4*)(smem + ((unsigned)(cidx * 16) ^ ((row & 7) << 4))) = v;
            }
        }
        // prefetch x fragments (independent of LDS stage; overlaps)
        const unsigned short* xrow = xt + (size_t)tx * BATCH * DIM;
        bf16x8 xa[16];
        if (kh == 0) {
#pragma unroll
            for (int ksl = 0; ksl < 8; ++ksl)
#pragma unroll
                for (int mt = 0; mt < 2; ++mt) {
                    int row = mh * 32 + mt * 16 + c15;
                    xa[ksl * 2 + mt] = *(const bf16x8*)(xrow + row * DIM + ksl * 32 + q * 8);
                }
        }
        __syncthreads();

        f32x4 acc[2][2] = {};
#pragma unroll
        for (int ksl = 0; ksl < 20; ++ksl) {
            int kk = kh * 640 + ksl * 32 + q * 8;
#pragma unroll
            for (int mt = 0; mt < 2; ++mt) {
                int row = mh * 32 + mt * 16 + c15;
                bf16x8 a;
                if (kh == 0 && ksl < 8) {
                    a = xa[ksl * 2 + mt];
                } else {
                    unsigned off = (unsigned)(row * 2048 + (kk - 256) * 2) ^ ((row & 7) << 4);
                    a = *(const bf16x8*)(smem + off);
                }
                acc[mt][0] = __builtin_amdgcn_mfma_f32_16x16x32_bf16(a, wreg[ksl],      acc[mt][0], 0, 0, 0);
                acc[mt][1] = __builtin_amdgcn_mfma_f32_16x16x32_bf16(a, wreg[20 + ksl], acc[mt][1], 0, 0, 0);
            }
        }
        if (kh == 1) {   // k-half-1 waves dump partials
            float* dp = (float*)(dumpbase + mh * 4096);
#pragma unroll
            for (int mt = 0; mt < 2; ++mt)
#pragma unroll
                for (int nt = 0; nt < 2; ++nt)
                    *(f32x4*)(dp + ((mt * 2 + nt) * 64 + lane) * 4) = acc[mt][nt];
        }
        __syncthreads();
        if (kh == 0) {   // reduce + gates + state update (waves 0,2 in parallel)
            const float* dp = (const float*)(dumpbase + mh * 4096);
            unsigned short* hnext = h_lstm + (size_t)(dir * 2 + ((t + 1) & 1)) * 65536;
            bool low = (lane & 8) == 0;
#pragma unroll
            for (int mt = 0; mt < 2; ++mt) {
                f32x4 g0 = acc[mt][0] + *(const f32x4*)(dp + ((mt * 2 + 0) * 64 + lane) * 4);
                f32x4 g1 = acc[mt][1] + *(const f32x4*)(dp + ((mt * 2 + 1) * 64 + lane) * 4);
                f32x4 av4;
#pragma unroll
                for (int r = 0; r < 4; ++r) {
                    float fo0 = __shfl(g0[r], lane ^ 8);   // f gate from partner lane
                    float fo1 = __shfl(g1[r], lane ^ 8);   // o gate from partner lane
                    int row = mh * 32 + mt * 16 + q * 4 + r;
                    float si = sigm(g0[r] + b_ii);
                    float sf = sigm(fo0 + b_ff);
                    float tg = tanhf(g1[r] + b_gg);
                    float so = sigm(fo1 + b_oo);
                    float cprev = auxf[row * 8 + hc];
                    float cn = sf * cprev + si * tg;
                    float hn = so * tanhf(cn);
                    float av = low ? hn * attw_l : 0.f;
                    av += __shfl_xor(av, 1); av += __shfl_xor(av, 2); av += __shfl_xor(av, 4);
                    av4[r] = av;
                    if (low) {
                        auxf[row * 8 + hc] = cn;
                        hnext[row * HID + colE] = f2bf(hn);
                    }
                }
                if (c15 == 0)
                    *(f32x4*)(att_part + (size_t)bid * 32768 + tx * 64 + (mh * 32 + mt * 16 + q * 4)) = av4;
            }
        }
        flag_barrier(flags, dir * 128, 128, dir * 128 + cg, (unsigned)(t + 1));
    }

    // =============== attention finalize ===============
    flag_barrier(flags, 256, 256, 256 + bid, 2u);
    {
        int i = tid & 127, half = tid >> 7;
        int item = bid * 128 + i;               // = t*64 + row
        int tt = item >> 6, row = item & 63;
        float s = 0.f;
        const float* p = att_part + (size_t)half * 128 * 32768 + item;
        for (int blk = 0; blk < 128; ++blk)
            s += p[(size_t)blk * 32768];
        float* red = (float*)dumpbase;
        if (half) red[i] = s;
        __syncthreads();
        if (!half)
            out[BATCH * COUT + row * SEQ + tt] = sigm(ATT_SIG_W * (s + red[i] + att_fc_b[0]));
    }
    flag_barrier(flags, 256, 256, 256 + bid, 3u);
    if (bid >= 64) return;

    // =============== TAGM loop (64 blocks) ===============
    bf16x8 wt[20];
    {
        const unsigned short* wp = Wtp + (size_t)(bid * 2 + kh) * 10240;
#pragma unroll
        for (int f = 0; f < 20; ++f)
            wt[f] = *(const bf16x8*)(wp + f * 512 + lane * 8);
    }
    int colT = bid * 16 + c15;
    float bbT = i2h_b[colT] + h2h_b[colT];
    for (int i = tid; i < 1024; i += 256) auxf[i] = 0.f;   // h master = 0
    __syncthreads();
    const float* attd = out + BATCH * COUT;

    for (int t = 0; t < SEQ; ++t) {
        {
            const uint4* src = (const uint4*)(h_tagm + (size_t)(t & 1) * 65536);
#pragma unroll 4
            for (int i = 0; i < 32; ++i) {
                int cidx = i * 256 + tid;
                int row = cidx >> 7;
                uint4 v = src[cidx];
                *(uint4*)(smem + ((unsigned)(cidx * 16) ^ ((row & 7) << 4))) = v;
            }
        }
        const unsigned short* xrow = xt + (size_t)t * BATCH * DIM;
        bf16x8 xa[16];
        if (kh == 0) {
#pragma unroll
            for (int ksl = 0; ksl < 8; ++ksl)
#pragma unroll
                for (int mt = 0; mt < 2; ++mt) {
                    int row = mh * 32 + mt * 16 + c15;
                    xa[ksl * 2 + mt] = *(const bf16x8*)(xrow + row * DIM + ksl * 32 + q * 8);
                }
        }
        __syncthreads();
        f32x4 acc[2] = {};
#pragma unroll
        for (int ksl = 0; ksl < 20; ++ksl) {
            int kk = kh * 640 + ksl * 32 + q * 8;
#pragma unroll
            for (int mt = 0; mt < 2; ++mt) {
                int row = mh * 32 + mt * 16 + c15;
                bf16x8 a;
                if (kh == 0 && ksl < 8) {
                    a = xa[ksl * 2 + mt];
                } else {
                    unsigned off = (unsigned)(row * 2048 + (kk - 256) * 2) ^ ((row & 7) << 4);
                    a = *(const bf16x8*)(smem + off);
                }
                acc[mt] = __builtin_amdgcn_mfma_f32_16x16x32_bf16(a, wt[ksl], acc[mt], 0, 0, 0);
            }
        }
        if (kh == 1) {
            float* dp = (float*)(dumpbase + mh * 2048);
            *(f32x4*)(dp + (0 * 64 + lane) * 4) = acc[0];
            *(f32x4*)(dp + (1 * 64 + lane) * 4) = acc[1];
        }
        __syncthreads();
        if (kh == 0) {
            const float* dp = (const float*)(dumpbase + mh * 2048);
            unsigned short* hnext = h_tagm + (size_t)((t + 1) & 1) * 65536;
#pragma unroll
            for (int mt = 0; mt < 2; ++mt) {
                f32x4 g = acc[mt] + *(const f32x4*)(dp + (mt * 64 + lane) * 4);
#pragma unroll
                for (int r = 0; r < 4; ++r) {
                    int row = mh * 32 + mt * 16 + q * 4 + r;
                    float cand = g[r] + bbT;
                    cand = cand > 0.f ? cand : 0.f;
                    float a = attd[row * SEQ + t];
                    float hold = auxf[row * 16 + c15];
                    float hn = a * cand + (1.f - a) * hold;
                    auxf[row * 16 + c15] = hn;
                    hnext[row * HID + colT] = f2bf(hn);
                }
            }
        }
        flag_barrier(flags, 512, 64, 512 + bid, (unsigned)(t + 1));
    }

    // dump final h (f32) for FC
    for (int i = tid; i < 1024; i += 256) {
        int row = i >> 4, cl = i & 15;
        h_f32[row * HID + bid * 16 + cl] = auxf[i];
    }
    flag_barrier(flags, 576, 64, 576 + bid, 1u);

    // =============== FC: out[b][c], block = batch row ===============
    {
        float* fcp = (float*)dumpbase;   // [2][128]
        int c = tid & 127, half = tid >> 7;
        const float* hrow = h_f32 + (size_t)bid * HID;
        float s = 0.f;
        for (int k = half * 512; k < half * 512 + 512; ++k)
            s += hrow[k] * fc_w[(size_t)k * COUT + c];
        fcp[half * 128 + c] = s;
        __syncthreads();
        if (tid < 128)
            out[bid * COUT + tid] = fcp[tid] + fcp[128 + tid] + fc_b[tid];
    }
}

extern "C" void kernel_launch(void* const* d_in, const int* in_sizes, int n_in,
                              void* d_out, int out_size, void* d_ws, size_t ws_size,
                              hipStream_t stream) {
    const float* x          = (const float*)d_in[0];
    const float* i2h_w      = (const float*)d_in[1];
    const float* i2h_b      = (const float*)d_in[2];
    const float* h2h_w      = (const float*)d_in[3];
    const float* h2h_b      = (const float*)d_in[4];
    const float* fc_w       = (const float*)d_in[5];
    const float* fc_b       = (const float*)d_in[6];
    const float* att_wi_fwd = (const float*)d_in[7];
    const float* att_wh_fwd = (const float*)d_in[8];
    const float* att_b_fwd  = (const float*)d_in[9];
    const float* att_wi_bwd = (const float*)d_in[10];
    const float* att_wh_bwd = (const float*)d_in[11];
    const float* att_b_bwd  = (const float*)d_in[12];
    const float* att_fc_w   = (const float*)d_in[13];
    const float* att_fc_b   = (const float*)d_in[14];
    float* out = (float*)d_out;

    char* ws = (char*)d_ws;
    // setup-phase (transposed f32->bf16 weights; dead after pack_* consume them)
    unsigned short* WfT = (unsigned short*)(ws + 0);          // 10485760
    unsigned short* WbT = (unsigned short*)(ws + 10485760);   // 10485760
    unsigned short* WtT = (unsigned short*)(ws + 20971520);   // 2621440 -> 23592960
    // packed fragment weights
    unsigned short* Wfp = (unsigned short*)(ws + 23592960);   // 10485760
    unsigned short* Wbp = (unsigned short*)(ws + 34078720);   // 10485760 -> 44564480
    unsigned short* Wtp = (unsigned short*)(ws + 17829888);   // 2621440 -> 20451328 (survives)
    // runtime region
    unsigned short* xtb    = (unsigned short*)(ws + 0);        // 16777216
    unsigned short* h_lstm = (unsigned short*)(ws + 16777216); // 524288
    unsigned short* h_tagm = (unsigned short*)(ws + 17301504); // 262144
    float*          h_f32  = (float*)(ws + 17563648);          // 262144
    unsigned*       flags  = (unsigned*)(ws + 17825792);       // 4096 -> 17829888
    // att_part ALIASES Wfp/Wbp + tail (weights are in registers after epoch-1 barrier)
    float*          att_part = (float*)(ws + 23592960);        // 256*32768*4 = 33554432 -> 57147392

    transpose_weights<<<20 * (NGATE / 64), 256, 0, stream>>>(att_wi_fwd, att_wh_fwd, WfT, NGATE);
    transpose_weights<<<20 * (NGATE / 64), 256, 0, stream>>>(att_wi_bwd, att_wh_bwd, WbT, NGATE);
    transpose_weights<<<20 * (HID / 64), 256, 0, stream>>>(i2h_w, h2h_w, WtT, HID);
    pack_lstm<<<256, 256, 0, stream>>>(WfT, Wfp);
    pack_lstm<<<256, 256, 0, stream>>>(WbT, Wbp);   // frees WbT; Wtp (17.8-20.5MB) written next
    pack_tagm<<<128, 256, 0, stream>>>(WtT, Wtp);
    transpose_x<<<(SEQ * BATCH * DIM + 255) / 256, 256, 0, stream>>>(x, xtb);
    // zero recurrent state + flags every call (replays mutate them)
    hipMemsetAsync(ws + 16777216, 0, 17829888 - 16777216, stream);

    static const int SMEM_BYTES = 131072 + 8192 + 4096;   // 143360
    hipFuncSetAttribute(reinterpret_cast<const void*>(tagm_fused),
                        hipFuncAttributeMaxDynamicSharedMemorySize, SMEM_BYTES);
    tagm_fused<<<256, 256, SMEM_BYTES, stream>>>(
        xtb, Wfp, Wbp, Wtp, att_b_fwd, att_b_bwd, att_fc_w, att_fc_b,
        i2h_b, h2h_b, fc_w, fc_b, h_lstm, h_tagm, h_f32, att_part, flags, out);
}

// Round 4
// 10520.740 us; speedup vs baseline: 2.5581x; 1.8557x over previous
//
#include <hip/hip_runtime.h>
#include <hip/hip_bf16.h>
#include <cstdint>
#include <cstddef>

constexpr int BATCH = 64;
constexpr int SEQ   = 512;
constexpr int DIM   = 256;
constexpr int HID   = 1024;
constexpr int COUT  = 128;
constexpr int KTOT  = DIM + HID;   // 1280
constexpr int NGATE = 4 * HID;     // 4096
constexpr float ATT_SIG_W = 3.0f;

using bf16x8 = __attribute__((ext_vector_type(8))) __bf16;
using f32x4  = __attribute__((ext_vector_type(4))) float;

__device__ __forceinline__ unsigned short f2bf(float f) {
    union { float f; unsigned u; } v; v.f = f;
    unsigned u = v.u;
    u += 0x7fffu + ((u >> 16) & 1u);
    return (unsigned short)(u >> 16);
}

__device__ __forceinline__ float sigm(float x) { return 1.f / (1.f + __expf(-x)); }

// system-scope (sc0 sc1) 2-byte store: write-through to coherent point, no L2 dirty line
__device__ __forceinline__ void store_short_wt(unsigned short* p, unsigned short v) {
    asm volatile("global_store_short %0, %1, off sc0 sc1"
                 :: "v"(p), "v"((unsigned)v) : "memory");
}

// global->LDS direct copy, 16B/lane, sc0|sc1 (aux=17): bypass L1+L2, read coherent L3
#define GLOAD_LDS_COHERENT(gptr, lptr)                                     \
    __builtin_amdgcn_global_load_lds(                                      \
        (const __attribute__((address_space(1))) void*)(gptr),             \
        (__attribute__((address_space(3))) void*)(lptr), 16, 0, 17)

// ---- weight transpose+convert: out[n][k] = bf16( k<DIM ? wi[k][n] : wh[k-DIM][n] )
__global__ void transpose_weights(const float* __restrict__ wi,
                                  const float* __restrict__ wh,
                                  unsigned short* __restrict__ out, int N) {
    __shared__ float tile[64][65];
    int ntiles = N >> 6;
    int kt = blockIdx.x / ntiles;
    int nt = blockIdx.x % ntiles;
    int k0 = kt << 6, n0 = nt << 6;
    int a = threadIdx.x & 63, g = threadIdx.x >> 6;
#pragma unroll
    for (int p = 0; p < 16; ++p) {
        int kr = p * 4 + g;
        int k = k0 + kr;
        const float* src = (k < DIM) ? (wi + (size_t)k * N) : (wh + (size_t)(k - DIM) * N);
        tile[kr][a] = src[n0 + a];
    }
    __syncthreads();
#pragma unroll
    for (int p = 0; p < 16; ++p) {
        int nr = p * 4 + g;
        out[(size_t)(n0 + nr) * KTOT + (k0 + a)] = f2bf(tile[a][nr]);
    }
}

// ---- x [B][T][D] f32 -> xt [T][B][D] bf16
__global__ void transpose_x(const float* __restrict__ x, unsigned short* __restrict__ xt) {
    size_t idx = (size_t)blockIdx.x * blockDim.x + threadIdx.x;
    if (idx >= (size_t)SEQ * BATCH * DIM) return;
    int d = idx % DIM;
    size_t r = idx / DIM;
    int b = r % BATCH;
    int t = r / BATCH;
    xt[idx] = f2bf(x[((size_t)b * SEQ + t) * DIM + d]);
}

// ---- pack LSTM weights into per-(colgroup, khalf) MFMA fragment order.
__global__ void pack_lstm(const unsigned short* __restrict__ WT,
                          unsigned short* __restrict__ out) {
    int cg = blockIdx.x >> 1, kh = blockIdx.x & 1;
    size_t base = (size_t)blockIdx.x * 20480;
#pragma unroll
    for (int j = 0; j < 80; ++j) {
        int idx = threadIdx.x * 80 + j;
        int frag = idx >> 9;
        int rem = idx & 511;
        int lane = rem >> 3, e = rem & 7;
        int nt = frag / 20, ksl = frag % 20;
        int p = nt * 16 + (lane & 15);
        int origcol = (p >> 3) * 1024 + cg * 8 + (p & 7);
        int k = kh * 640 + ksl * 32 + ((lane >> 4) & 3) * 8 + e;
        out[base + idx] = WT[(size_t)origcol * KTOT + k];
    }
}

// ---- pack TAGM weights: region (cg,kh): 20 frags x 1024B; col = cg*16+(lane&15)
__global__ void pack_tagm(const unsigned short* __restrict__ WT,
                          unsigned short* __restrict__ out) {
    int cg = blockIdx.x >> 1, kh = blockIdx.x & 1;
    size_t base = (size_t)blockIdx.x * 10240;
#pragma unroll
    for (int j = 0; j < 40; ++j) {
        int idx = threadIdx.x * 40 + j;
        int ksl = idx >> 9;
        int rem = idx & 511;
        int lane = rem >> 3, e = rem & 7;
        int origcol = cg * 16 + (lane & 15);
        int k = kh * 640 + ksl * 32 + ((lane >> 4) & 3) * 8 + e;
        out[base + idx] = WT[(size_t)origcol * KTOT + k];
    }
}

// ---- LIGHT per-step barrier: NO cache-maintenance fences.
// Correctness: all cross-block data was stored write-through (sc0 sc1) and drained
// by vmcnt(0) before the flag store; readers bypass L1/L2 (sc0 sc1 loads).
__device__ __forceinline__ void flag_light(unsigned* flags, int base, int cnt,
                                           int myidx, unsigned epoch) {
    asm volatile("s_waitcnt vmcnt(0)" ::: "memory");  // each wave drains its own WT stores
    __syncthreads();
    if (threadIdx.x == 0)
        __hip_atomic_store(flags + myidx, epoch, __ATOMIC_RELAXED, __HIP_MEMORY_SCOPE_AGENT);
    if (threadIdx.x < 64) {
        for (;;) {
            bool ok = true;
            for (int j = (int)threadIdx.x; j < cnt; j += 64)
                ok &= (__hip_atomic_load(flags + base + j, __ATOMIC_RELAXED,
                                         __HIP_MEMORY_SCOPE_AGENT) >= epoch);
            if (__all(ok)) break;
            __builtin_amdgcn_s_sleep(1);
        }
    }
    __syncthreads();
}

// ---- HEAVY barrier (phase boundaries only): full release/acquire fences for
// normally-cached traffic (att_part aliasing, att output, h_f32).
__device__ __forceinline__ void flag_barrier(unsigned* flags, int base, int cnt,
                                             int myidx, unsigned epoch) {
    __syncthreads();
    if (threadIdx.x == 0) {
        __builtin_amdgcn_fence(__ATOMIC_RELEASE, "agent");   // wbl2
        __hip_atomic_store(flags + myidx, epoch, __ATOMIC_RELAXED, __HIP_MEMORY_SCOPE_AGENT);
    }
    if (threadIdx.x < 64) {
        for (;;) {
            bool ok = true;
            for (int j = (int)threadIdx.x; j < cnt; j += 64)
                ok &= (__hip_atomic_load(flags + base + j, __ATOMIC_RELAXED,
                                         __HIP_MEMORY_SCOPE_AGENT) >= epoch);
            if (__all(ok)) break;
            __builtin_amdgcn_s_sleep(1);
        }
        if (threadIdx.x == 0)
            __builtin_amdgcn_fence(__ATOMIC_ACQUIRE, "agent");   // inv
    }
    __syncthreads();
}

// ======== the persistent fused kernel ========
// grid 256 x 256thr; LDS 140KiB -> 1 block/CU -> all blocks co-resident.
// LSTM: block = (dir = bid&1, cg = bid>>1 : 8 h-cols x 4 gates). wave = (mh, kh).
// TAGM (bid<64): block = 16 h-cols.
__global__ __launch_bounds__(256)
void tagm_fused(const unsigned short* __restrict__ xt,
                const unsigned short* __restrict__ Wfp,
                const unsigned short* __restrict__ Wbp,
                const unsigned short* __restrict__ Wtp,
                const float* __restrict__ bias_f, const float* __restrict__ bias_b,
                const float* __restrict__ attw, const float* __restrict__ att_fc_b,
                const float* __restrict__ i2h_b, const float* __restrict__ h2h_b,
                const float* __restrict__ fc_w, const float* __restrict__ fc_b,
                unsigned short* __restrict__ h_lstm,  // [2][2][64][1024] bf16
                unsigned short* __restrict__ h_tagm,  // [2][64][1024] bf16
                float* __restrict__ h_f32,            // [64][1024]
                float* __restrict__ att_part,         // [256 blk][512*64] f32 (aliases Wfp/Wbp!)
                unsigned* __restrict__ flags,         // [640]
                float* __restrict__ out) {
    extern __shared__ char smem[];                  // [0,131072): h stage (swizzled)
    char* dumpbase = smem + 131072;                 // 8 KB acc dump
    float* auxf = (float*)(smem + 131072 + 8192);   // 4 KB: LSTM c / TAGM h master

    int tid = threadIdx.x;
    int wave = tid >> 6, lane = tid & 63;
    int bid = blockIdx.x;
    int dir = bid & 1, cg = bid >> 1;
    int mh = wave >> 1, kh = wave & 1;
    int q = lane >> 4, c15 = lane & 15;

    // ---- LSTM weight fragments -> registers
    bf16x8 wreg[40];
    {
        const unsigned short* wp = (dir ? Wbp : Wfp) + (size_t)(cg * 2 + kh) * 20480;
#pragma unroll
        for (int f = 0; f < 40; ++f)
            wreg[f] = *(const bf16x8*)(wp + f * 512 + lane * 8);
    }
    int hc = lane & 7;
    int colE = cg * 8 + hc;
    const float* bias = dir ? bias_b : bias_f;
    float b_ii = bias[colE], b_ff = bias[HID + colE];
    float b_gg = bias[2 * HID + colE], b_oo = bias[3 * HID + colE];
    float attw_l = attw[dir * HID + colE];

    for (int i = tid; i < 512; i += 256) auxf[i] = 0.f;   // c = 0

    // weights in regs (vmcnt-drained by flag_light) before att_part may clobber Wfp/Wbp
    flag_light(flags, 256, 256, 256 + bid, 1u);

    // =============== LSTM loop ===============
    for (int t = 0; t < SEQ; ++t) {
        int tx = dir ? (SEQ - 1 - t) : t;
        {   // stage h_prev -> LDS via global_load_lds (coherent bypass), pre-swizzled src
            const char* hsrc = (const char*)h_lstm + (size_t)(dir * 2 + (t & 1)) * 131072;
            char* lbase = smem + (size_t)(tid & 192) * 16;
#pragma unroll
            for (int i = 0; i < 32; ++i) {
                int s = i * 256 + tid;                 // linear 16B-chunk index
                int g = s ^ ((s >> 7) & 7);            // involution: swizzled source chunk
                GLOAD_LDS_COHERENT(hsrc + (size_t)g * 16, lbase + (size_t)i * 4096);
            }
        }
        // prefetch x fragments (normal cached loads; xt is read-only and stays in L2)
        const unsigned short* xrow = xt + (size_t)tx * BATCH * DIM;
        bf16x8 xa[16];
        if (kh == 0) {
#pragma unroll
            for (int ksl = 0; ksl < 8; ++ksl)
#pragma unroll
                for (int mt = 0; mt < 2; ++mt) {
                    int row = mh * 32 + mt * 16 + c15;
                    xa[ksl * 2 + mt] = *(const bf16x8*)(xrow + row * DIM + ksl * 32 + q * 8);
                }
        }
        __syncthreads();   // drains global_load_lds (vmcnt) + xa, then barrier

        f32x4 acc[2][2] = {};
#pragma unroll
        for (int ksl = 0; ksl < 20; ++ksl) {
            int kk = kh * 640 + ksl * 32 + q * 8;
#pragma unroll
            for (int mt = 0; mt < 2; ++mt) {
                int row = mh * 32 + mt * 16 + c15;
                bf16x8 a;
                if (kh == 0 && ksl < 8) {
                    a = xa[ksl * 2 + mt];
                } else {
                    unsigned off = (unsigned)(row * 2048 + (kk - 256) * 2) ^ ((row & 7) << 4);
                    a = *(const bf16x8*)(smem + off);
                }
                acc[mt][0] = __builtin_amdgcn_mfma_f32_16x16x32_bf16(a, wreg[ksl],      acc[mt][0], 0, 0, 0);
                acc[mt][1] = __builtin_amdgcn_mfma_f32_16x16x32_bf16(a, wreg[20 + ksl], acc[mt][1], 0, 0, 0);
            }
        }
        if (kh == 1) {   // k-half-1 waves dump partials
            float* dp = (float*)(dumpbase + mh * 4096);
#pragma unroll
            for (int mt = 0; mt < 2; ++mt)
#pragma unroll
                for (int nt = 0; nt < 2; ++nt)
                    *(f32x4*)(dp + ((mt * 2 + nt) * 64 + lane) * 4) = acc[mt][nt];
        }
        __syncthreads();
        if (kh == 0) {   // reduce + gates + state update (waves 0,2 in parallel)
            const float* dp = (const float*)(dumpbase + mh * 4096);
            unsigned short* hnext = h_lstm + (size_t)(dir * 2 + ((t + 1) & 1)) * 65536;
            bool low = (lane & 8) == 0;
#pragma unroll
            for (int mt = 0; mt < 2; ++mt) {
                f32x4 g0 = acc[mt][0] + *(const f32x4*)(dp + ((mt * 2 + 0) * 64 + lane) * 4);
                f32x4 g1 = acc[mt][1] + *(const f32x4*)(dp + ((mt * 2 + 1) * 64 + lane) * 4);
                f32x4 av4;
#pragma unroll
                for (int r = 0; r < 4; ++r) {
                    float fo0 = __shfl(g0[r], lane ^ 8);   // f gate from partner lane
                    float fo1 = __shfl(g1[r], lane ^ 8);   // o gate from partner lane
                    int row = mh * 32 + mt * 16 + q * 4 + r;
                    float si = sigm(g0[r] + b_ii);
                    float sf = sigm(fo0 + b_ff);
                    float tg = tanhf(g1[r] + b_gg);
                    float so = sigm(fo1 + b_oo);
                    float cprev = auxf[row * 8 + hc];
                    float cn = sf * cprev + si * tg;
                    float hn = so * tanhf(cn);
                    float av = low ? hn * attw_l : 0.f;
                    av += __shfl_xor(av, 1); av += __shfl_xor(av, 2); av += __shfl_xor(av, 4);
                    av4[r] = av;
                    if (low) {
                        auxf[row * 8 + hc] = cn;
                        store_short_wt(hnext + row * HID + colE, f2bf(hn));   // write-through
                    }
                }
                if (c15 == 0)
                    *(f32x4*)(att_part + (size_t)bid * 32768 + tx * 64 + (mh * 32 + mt * 16 + q * 4)) = av4;
            }
        }
        flag_light(flags, dir * 128, 128, dir * 128 + cg, (unsigned)(t + 1));
    }

    // =============== attention finalize ===============
    flag_barrier(flags, 256, 256, 256 + bid, 2u);   // heavy: att_part was cached-written
    {
        int i = tid & 127, half = tid >> 7;
        int item = bid * 128 + i;               // = t*64 + row
        int tt = item >> 6, row = item & 63;
        float s = 0.f;
        const float* p = att_part + (size_t)half * 128 * 32768 + item;
        for (int blk = 0; blk < 128; ++blk)
            s += p[(size_t)blk * 32768];
        float* red = (float*)dumpbase;
        if (half) red[i] = s;
        __syncthreads();
        if (!half)
            out[BATCH * COUT + row * SEQ + tt] = sigm(ATT_SIG_W * (s + red[i] + att_fc_b[0]));
    }
    flag_barrier(flags, 256, 256, 256 + bid, 3u);   // heavy: att out cached-written
    if (bid >= 64) return;

    // =============== TAGM loop (64 blocks) ===============
    bf16x8 wt[20];
    {
        const unsigned short* wp = Wtp + (size_t)(bid * 2 + kh) * 10240;
#pragma unroll
        for (int f = 0; f < 20; ++f)
            wt[f] = *(const bf16x8*)(wp + f * 512 + lane * 8);
    }
    int colT = bid * 16 + c15;
    float bbT = i2h_b[colT] + h2h_b[colT];
    for (int i = tid; i < 1024; i += 256) auxf[i] = 0.f;   // h master = 0
    __syncthreads();
    const float* attd = out + BATCH * COUT;

    for (int t = 0; t < SEQ; ++t) {
        {
            const char* hsrc = (const char*)h_tagm + (size_t)(t & 1) * 131072;
            char* lbase = smem + (size_t)(tid & 192) * 16;
#pragma unroll
            for (int i = 0; i < 32; ++i) {
                int s = i * 256 + tid;
                int g = s ^ ((s >> 7) & 7);
                GLOAD_LDS_COHERENT(hsrc + (size_t)g * 16, lbase + (size_t)i * 4096);
            }
        }
        const unsigned short* xrow = xt + (size_t)t * BATCH * DIM;
        bf16x8 xa[16];
        if (kh == 0) {
#pragma unroll
            for (int ksl = 0; ksl < 8; ++ksl)
#pragma unroll
                for (int mt = 0; mt < 2; ++mt) {
                    int row = mh * 32 + mt * 16 + c15;
                    xa[ksl * 2 + mt] = *(const bf16x8*)(xrow + row * DIM + ksl * 32 + q * 8);
                }
        }
        __syncthreads();
        f32x4 acc[2] = {};
#pragma unroll
        for (int ksl = 0; ksl < 20; ++ksl) {
            int kk = kh * 640 + ksl * 32 + q * 8;
#pragma unroll
            for (int mt = 0; mt < 2; ++mt) {
                int row = mh * 32 + mt * 16 + c15;
                bf16x8 a;
                if (kh == 0 && ksl < 8) {
                    a = xa[ksl * 2 + mt];
                } else {
                    unsigned off = (unsigned)(row * 2048 + (kk - 256) * 2) ^ ((row & 7) << 4);
                    a = *(const bf16x8*)(smem + off);
                }
                acc[mt] = __builtin_amdgcn_mfma_f32_16x16x32_bf16(a, wt[ksl], acc[mt], 0, 0, 0);
            }
        }
        if (kh == 1) {
            float* dp = (float*)(dumpbase + mh * 2048);
            *(f32x4*)(dp + (0 * 64 + lane) * 4) = acc[0];
            *(f32x4*)(dp + (1 * 64 + lane) * 4) = acc[1];
        }
        __syncthreads();
        if (kh == 0) {
            const float* dp = (const float*)(dumpbase + mh * 2048);
            unsigned short* hnext = h_tagm + (size_t)((t + 1) & 1) * 65536;
#pragma unroll
            for (int mt = 0; mt < 2; ++mt) {
                f32x4 g = acc[mt] + *(const f32x4*)(dp + (mt * 64 + lane) * 4);
#pragma unroll
                for (int r = 0; r < 4; ++r) {
                    int row = mh * 32 + mt * 16 + q * 4 + r;
                    float cand = g[r] + bbT;
                    cand = cand > 0.f ? cand : 0.f;
                    float a = attd[row * SEQ + t];
                    float hold = auxf[row * 16 + c15];
                    float hn = a * cand + (1.f - a) * hold;
                    auxf[row * 16 + c15] = hn;
                    store_short_wt(hnext + row * HID + colT, f2bf(hn));   // write-through
                }
            }
        }
        flag_light(flags, 512, 64, 512 + bid, (unsigned)(t + 1));
    }

    // dump final h (f32) for FC
    for (int i = tid; i < 1024; i += 256) {
        int row = i >> 4, cl = i & 15;
        h_f32[row * HID + bid * 16 + cl] = auxf[i];
    }
    flag_barrier(flags, 576, 64, 576 + bid, 1u);   // heavy: h_f32 cached-written

    // =============== FC: out[b][c], block = batch row ===============
    {
        float* fcp = (float*)dumpbase;   // [2][128]
        int c = tid & 127, half = tid >> 7;
        const float* hrow = h_f32 + (size_t)bid * HID;
        float s = 0.f;
        for (int k = half * 512; k < half * 512 + 512; ++k)
            s += hrow[k] * fc_w[(size_t)k * COUT + c];
        fcp[half * 128 + c] = s;
        __syncthreads();
        if (tid < 128)
            out[bid * COUT + tid] = fcp[tid] + fcp[128 + tid] + fc_b[tid];
    }
}

extern "C" void kernel_launch(void* const* d_in, const int* in_sizes, int n_in,
                              void* d_out, int out_size, void* d_ws, size_t ws_size,
                              hipStream_t stream) {
    const float* x          = (const float*)d_in[0];
    const float* i2h_w      = (const float*)d_in[1];
    const float* i2h_b      = (const float*)d_in[2];
    const float* h2h_w      = (const float*)d_in[3];
    const float* h2h_b      = (const float*)d_in[4];
    const float* fc_w       = (const float*)d_in[5];
    const float* fc_b       = (const float*)d_in[6];
    const float* att_wi_fwd = (const float*)d_in[7];
    const float* att_wh_fwd = (const float*)d_in[8];
    const float* att_b_fwd  = (const float*)d_in[9];
    const float* att_wi_bwd = (const float*)d_in[10];
    const float* att_wh_bwd = (const float*)d_in[11];
    const float* att_b_bwd  = (const float*)d_in[12];
    const float* att_fc_w   = (const float*)d_in[13];
    const float* att_fc_b   = (const float*)d_in[14];
    float* out = (float*)d_out;

    char* ws = (char*)d_ws;
    // setup-phase (transposed f32->bf16 weights; dead after pack_* consume them)
    unsigned short* WfT = (unsigned short*)(ws + 0);          // 10485760
    unsigned short* WbT = (unsigned short*)(ws + 10485760);   // 10485760
    unsigned short* WtT = (unsigned short*)(ws + 20971520);   // 2621440 -> 23592960
    // packed fragment weights
    unsigned short* Wfp = (unsigned short*)(ws + 23592960);   // 10485760
    unsigned short* Wbp = (unsigned short*)(ws + 34078720);   // 10485760 -> 44564480
    unsigned short* Wtp = (unsigned short*)(ws + 17829888);   // 2621440 -> 20451328 (survives)
    // runtime region
    unsigned short* xtb    = (unsigned short*)(ws + 0);        // 16777216
    unsigned short* h_lstm = (unsigned short*)(ws + 16777216); // 524288
    unsigned short* h_tagm = (unsigned short*)(ws + 17301504); // 262144
    float*          h_f32  = (float*)(ws + 17563648);          // 262144
    unsigned*       flags  = (unsigned*)(ws + 17825792);       // 4096 -> 17829888
    // att_part ALIASES Wfp/Wbp + tail (weights are in registers after epoch-1 barrier)
    float*          att_part = (float*)(ws + 23592960);        // 256*32768*4 = 33554432 -> 57147392

    transpose_weights<<<20 * (NGATE / 64), 256, 0, stream>>>(att_wi_fwd, att_wh_fwd, WfT, NGATE);
    transpose_weights<<<20 * (NGATE / 64), 256, 0, stream>>>(att_wi_bwd, att_wh_bwd, WbT, NGATE);
    transpose_weights<<<20 * (HID / 64), 256, 0, stream>>>(i2h_w, h2h_w, WtT, HID);
    pack_lstm<<<256, 256, 0, stream>>>(WfT, Wfp);
    pack_lstm<<<256, 256, 0, stream>>>(WbT, Wbp);   // frees WbT; Wtp (17.8-20.5MB) written next
    pack_tagm<<<128, 256, 0, stream>>>(WtT, Wtp);
    transpose_x<<<(SEQ * BATCH * DIM + 255) / 256, 256, 0, stream>>>(x, xtb);
    // zero recurrent state + flags every call (replays mutate them)
    hipMemsetAsync(ws + 16777216, 0, 17829888 - 16777216, stream);

    static const int SMEM_BYTES = 131072 + 8192 + 4096;   // 143360
    hipFuncSetAttribute(reinterpret_cast<const void*>(tagm_fused),
                        hipFuncAttributeMaxDynamicSharedMemorySize, SMEM_BYTES);
    tagm_fused<<<256, 256, SMEM_BYTES, stream>>>(
        xtb, Wfp, Wbp, Wtp, att_b_fwd, att_b_bwd, att_fc_w, att_fc_b,
        i2h_b, h2h_b, fc_w, fc_b, h_lstm, h_tagm, h_f32, att_part, flags, out);
}